// Round 9
// baseline (321.566 us; speedup 1.0000x reference)
//
#include <hip/hip_runtime.h>
#include <stdint.h>

constexpr int kHW = 16384;   // 128*128 pixels (grid shared across batch)
constexpr int kB  = 4;
constexpr int kM  = 256;     // tokens

typedef _Float16 half8 __attribute__((ext_vector_type(8)));  // 8 fp16 (4 VGPRs)
typedef __attribute__((ext_vector_type(4))) float f32x4;     // MFMA accum

// ---------------- helpers ----------------
__device__ __forceinline__ unsigned short f2h(float f) {
  _Float16 h = (_Float16)f;
  return __builtin_bit_cast(unsigned short, h);
}
__device__ __forceinline__ float h2f(unsigned short u) {
  return (float)__builtin_bit_cast(_Float16, u);
}
// XOR swizzle for 256-short-wide rows (8-short chunks): conflict-free b128 A-reads.
__device__ __forceinline__ int swz256(int row, int col) {
  int ch = col >> 3;
  ch = (ch & ~7) | ((ch ^ row) & 7);
  return row * 256 + ch * 8 + (col & 7);
}

// ---------------- kernel 0: weight prep (transpose + fp16) ----------------
__global__ __launch_bounds__(256) void wprep_kernel(
    const float* __restrict__ tooW, const float* __restrict__ modW0,
    const float* __restrict__ modW1, const float* __restrict__ hvW0,
    const float* __restrict__ qW, const float* __restrict__ bwW0,
    const float* __restrict__ bwW1, const float* __restrict__ toqW,
    unsigned short* __restrict__ tooWt, unsigned short* __restrict__ modW0t,
    unsigned short* __restrict__ modW1t, unsigned short* __restrict__ hvW0t,
    unsigned short* __restrict__ qWt, unsigned short* __restrict__ bw0t,
    unsigned short* __restrict__ bw1t, unsigned short* __restrict__ toqWt)
{
  int m = blockIdx.x, tid = threadIdx.x;
  const float* Ws[8] = {tooW, modW0, modW1, hvW0, qW, bwW0, bwW1, toqW};
  unsigned short* Wts[8] = {tooWt, modW0t, modW1t, hvW0t, qWt, bw0t, bw1t, toqWt};
  const int Ks[8] = {128, 256, 256, 256, 64, 64, 64, 256};
  const int Ns[8] = {256, 256, 256, 256, 256, 256, 256, 128};
  const float* W = Ws[m];
  unsigned short* Wt = Wts[m];
  int K = Ks[m], N = Ns[m];
  if (tid < N) {
    for (int kb = 0; kb < K / 8; kb++) {
      unsigned short sv[8];
#pragma unroll
      for (int i = 0; i < 8; i++)
        sv[i] = f2h(W[(kb * 8 + i) * N + tid]);   // coalesced across tid
      *(uint4*)&Wt[tid * K + kb * 8] = *(const uint4*)sv;
    }
  }
}

// ---------------- kernel 1: kv = tokens @ tokvW -> K natural + V transposed, fp16 ----------------
__global__ __launch_bounds__(256) void kv_kernel(
    const float* __restrict__ tokens, const float* __restrict__ tokvW,
    unsigned short* __restrict__ kn_ws, unsigned short* __restrict__ vt_ws)
{
  __shared__ __align__(16) float tok[256];
  int b = blockIdx.y, j = blockIdx.x, c = threadIdx.x;
  tok[c] = tokens[(b * kM + j) * 256 + c];
  __syncthreads();
  float acc = 0.f;
  for (int i4 = 0; i4 < 64; i4++) {
    float4 t4 = *(const float4*)&tok[i4 * 4];
    acc += t4.x * tokvW[(i4*4+0)*256 + c] + t4.y * tokvW[(i4*4+1)*256 + c]
         + t4.z * tokvW[(i4*4+2)*256 + c] + t4.w * tokvW[(i4*4+3)*256 + c];
  }
  unsigned short hv = f2h(acc);
  if (c < 128) {
    int h = c >> 6, dd = c & 63;
    kn_ws[((size_t)(b*2+h)*256 + j) * 64 + dd] = hv;
  } else {
    int c2 = c - 128;
    int h = c2 >> 6, dd = c2 & 63;
    vt_ws[((size_t)(b*2+h)*64 + dd) * 256 + j] = hv;
  }
}

// ---------------- kernel 2: MFMA per-pixel features (R6-proven) ----------------
constexpr int kFPitch = 72;
constexpr int kXPitch = 264;

__global__ __launch_bounds__(256, 2) void feat_kernel(
    const float* __restrict__ coords,
    const float* __restrict__ Bq, const float* __restrict__ Bl0, const float* __restrict__ Bl1,
    const float* __restrict__ qb, const float* __restrict__ bwb0, const float* __restrict__ bwb1,
    const unsigned short* __restrict__ qWt, const unsigned short* __restrict__ bw0t,
    const unsigned short* __restrict__ bw1t, const unsigned short* __restrict__ toqWt,
    unsigned short* __restrict__ qc_ws,
    unsigned short* __restrict__ h0_hf, unsigned short* __restrict__ h1_hf)
{
  __shared__ __align__(16) unsigned short ff_s[3][32][kFPitch];
  __shared__ __align__(16) unsigned short xq_s[32][kXPitch];
  __shared__ float coords_s[64];

  int tid = threadIdx.x;
  int px0 = blockIdx.x * 32;
  int w = tid >> 6, ln = tid & 63;
  int c = ln & 15, q = ln >> 4;

  if (tid < 64) coords_s[tid] = coords[px0 * 2 + tid];
  __syncthreads();

#pragma unroll
  for (int r = 0; r < 24; r++) {
    int v = r * 256 + tid;
    int mat = v >> 11;
    int p = (v >> 6) & 31;
    int f = v & 63;
    int fr = f & 31;
    const float* Bm = (mat == 0) ? Bq : (mat == 1 ? Bl0 : Bl1);
    float x = coords_s[p * 2 + 0];
    float y = coords_s[p * 2 + 1];
    float proj = 6.283185307179586f * (x * Bm[fr*2+0] + y * Bm[fr*2+1]);
    float s, cc;
    __sincosf(proj, &s, &cc);
    ff_s[mat][p][f] = f2h((f < 32) ? cc : s);
  }
  __syncthreads();

  const f32x4 zero4 = {0.f, 0.f, 0.f, 0.f};

  for (int mat = 0; mat < 3; mat++) {
    const unsigned short* Wt = (mat == 0) ? qWt : (mat == 1 ? bw0t : bw1t);
    const float* bias = (mat == 0) ? qb : (mat == 1 ? bwb0 : bwb1);
    f32x4 acc[8];
#pragma unroll
    for (int i = 0; i < 8; i++) acc[i] = zero4;
#pragma unroll
    for (int ks = 0; ks < 2; ks++) {
      int koff = ks * 32 + q * 8;
      half8 bfr[4];
#pragma unroll
      for (int nt = 0; nt < 4; nt++)
        bfr[nt] = *(const half8*)(Wt + (size_t)(w*64 + nt*16 + c) * 64 + koff);
      half8 afr[2];
#pragma unroll
      for (int mt = 0; mt < 2; mt++)
        afr[mt] = *(const half8*)(&ff_s[mat][mt*16 + c][koff]);
#pragma unroll
      for (int mt = 0; mt < 2; mt++)
#pragma unroll
        for (int nt = 0; nt < 4; nt++)
          acc[mt*4+nt] = __builtin_amdgcn_mfma_f32_16x16x32_f16(afr[mt], bfr[nt], acc[mt*4+nt], 0, 0, 0);
    }
    float bv[4];
#pragma unroll
    for (int nt = 0; nt < 4; nt++) bv[nt] = bias[w*64 + nt*16 + c];
#pragma unroll
    for (int mt = 0; mt < 2; mt++)
#pragma unroll
      for (int nt = 0; nt < 4; nt++)
#pragma unroll
        for (int rg = 0; rg < 4; rg++) {
          int row = mt*16 + q*4 + rg, col = w*64 + nt*16 + c;
          unsigned short hv = f2h(fmaxf(acc[mt*4+nt][rg] + bv[nt], 0.f));
          if (mat == 0)      xq_s[row][col] = hv;
          else if (mat == 1) h0_hf[((size_t)(px0 + row)) * 256 + col] = hv;
          else               h1_hf[((size_t)(px0 + row)) * 256 + col] = hv;
        }
  }
  __syncthreads();

  {
    f32x4 acc2[4];
#pragma unroll
    for (int i = 0; i < 4; i++) acc2[i] = zero4;
#pragma unroll
    for (int kt = 0; kt < 8; kt++) {
      int koff = kt * 32 + q * 8;
      half8 bfr[2];
#pragma unroll
      for (int nt = 0; nt < 2; nt++)
        bfr[nt] = *(const half8*)(toqWt + (size_t)(w*32 + nt*16 + c) * 256 + koff);
      half8 afr[2];
#pragma unroll
      for (int mt = 0; mt < 2; mt++)
        afr[mt] = *(const half8*)(&xq_s[mt*16 + c][koff]);
#pragma unroll
      for (int mt = 0; mt < 2; mt++)
#pragma unroll
        for (int nt = 0; nt < 2; nt++)
          acc2[mt*2+nt] = __builtin_amdgcn_mfma_f32_16x16x32_f16(afr[mt], bfr[nt], acc2[mt*2+nt], 0, 0, 0);
    }
#pragma unroll
    for (int mt = 0; mt < 2; mt++)
#pragma unroll
      for (int nt = 0; nt < 2; nt++)
#pragma unroll
        for (int rg = 0; rg < 4; rg++) {
          int row = mt*16 + q*4 + rg, col = w*32 + nt*16 + c;
          qc_ws[((size_t)(px0 + row)) * 128 + col] = f2h(acc2[mt*2+nt][rg]);
        }
  }
}

// ---------------- kernel 3: FUSED attention + MLP chain ----------------
// Block = 16 px, 4 waves; wave w = batch w. Attn phase: wave-private, barrier-free
// (M=16 px, N=256 tokens, K=64; softmax intra-wave shfl; P band swizzled in LDS).
// o lands directly in buf0 (row = w*16+px), then the R6-proven MLP chain runs.
// C layout (m89-verified): col = lane&15, row = (lane>>4)*4 + reg.
constexpr int kPitch = 264;   // fp16 LDS pitch for mlp tiles

template <int KD>
__device__ __forceinline__ void gemm4(
    const unsigned short* abuf, const unsigned short* wt,
    f32x4* acc /*[4*4]*/, int c, int q)
{
#pragma unroll
  for (int ks = 0; ks < KD / 32; ks++) {
    int koff = ks * 32 + q * 8;
    half8 bfr[4];
#pragma unroll
    for (int nt = 0; nt < 4; nt++)
      bfr[nt] = *(const half8*)(wt + (nt * 16 + c) * KD + koff);
    half8 afr[4];
#pragma unroll
    for (int mt = 0; mt < 4; mt++)
      afr[mt] = *(const half8*)(abuf + (mt * 16 + c) * kPitch + koff);
#pragma unroll
    for (int mt = 0; mt < 4; mt++)
#pragma unroll
      for (int nt = 0; nt < 4; nt++)
        acc[mt * 4 + nt] = __builtin_amdgcn_mfma_f32_16x16x32_f16(afr[mt], bfr[nt], acc[mt * 4 + nt], 0, 0, 0);
  }
}

__global__ __launch_bounds__(256, 2) void fused_kernel(
    const unsigned short* __restrict__ kn_ws,
    const unsigned short* __restrict__ vt_ws,
    const unsigned short* __restrict__ qc_ws,
    const float* __restrict__ coords,
    const unsigned short* __restrict__ h0_hf, const unsigned short* __restrict__ h1_hf,
    const unsigned short* __restrict__ tooWt, const float* __restrict__ toob,
    const unsigned short* __restrict__ modW0t, const float* __restrict__ modb0,
    const unsigned short* __restrict__ modW1t, const float* __restrict__ modb1,
    const unsigned short* __restrict__ hvW0t, const float* __restrict__ hvb0,
    const float* __restrict__ outW0, const float* __restrict__ outb0,
    const float* __restrict__ outW1, const float* __restrict__ outb1,
    float* __restrict__ dout)
{
  __shared__ __align__(16) unsigned short buf0[64 * kPitch];  // o -> m0 (hv0)
  __shared__ __align__(16) unsigned short regB[21120];        // P_s (attn) | buf1 (mod->S)
  __shared__ __align__(16) unsigned short hbuf[16 * kPitch];  // h0, then h1
  __shared__ __align__(16) float scratch[64 * 3 * 4];

  unsigned short* buf1  = regB;
  int tid = threadIdx.x;
  int px0 = blockIdx.x * 16;
  int w = tid >> 6, ln = tid & 63;    // wave w = batch w
  int c = ln & 15, q = ln >> 4;
  unsigned short* Pband = regB + w * 4096;   // wave-private 16x256 band

  const f32x4 zero4 = {0.f, 0.f, 0.f, 0.f};

  // ---- stage h0 early (hbuf is disjoint from P bands) ----
#pragma unroll
  for (int i = 0; i < 2; i++) {
    int idx = i * 256 + tid;              // 512 x uint4
    int p = idx >> 5, c8 = (idx & 31) * 8;
    uint4 v = *(const uint4*)(h0_hf + ((size_t)(px0 + p)) * 256 + c8);
    *(uint4*)&hbuf[p * kPitch + c8] = v;
  }

  // ---- per-lane t values for owned rows (px = px0 + q*4 + rg) ----
  float tv[4];
#pragma unroll
  for (int rg = 0; rg < 4; rg++) {
    int px = px0 + q*4 + rg;
    float x = coords[px*2 + 0], y = coords[px*2 + 1];
    int r = min(max((int)(x * 16.0f), 0), 15);
    int cl = min(max((int)(y * 16.0f), 0), 15);
    tv[rg] = (float)(r * 16 + cl) * (1.0f / 256.0f);
  }

  // ================= attention phase (barrier-free, wave = batch) =================
  for (int h = 0; h < 2; h++) {
    // QK^T: M=16 (px), N=256 (16 nt), K=64
    f32x4 acc[16];
#pragma unroll
    for (int i = 0; i < 16; i++) acc[i] = zero4;
    const unsigned short* kbase = kn_ws + (size_t)(w*2+h) * 256 * 64;
    const unsigned short* qrow = qc_ws + (size_t)(px0 + c) * 128 + h*64;
    half8 a0 = *(const half8*)(qrow + q*8);
    half8 a1 = *(const half8*)(qrow + 32 + q*8);
#pragma unroll
    for (int nt = 0; nt < 16; nt++) {
      const unsigned short* kr = kbase + (size_t)(nt*16 + c) * 64 + q*8;
      half8 b0 = *(const half8*)(kr);
      half8 b1 = *(const half8*)(kr + 32);
      acc[nt] = __builtin_amdgcn_mfma_f32_16x16x32_f16(a0, b0, acc[nt], 0, 0, 0);
      acc[nt] = __builtin_amdgcn_mfma_f32_16x16x32_f16(a1, b1, acc[nt], 0, 0, 0);
    }

    // bias + scale; row max (intra-wave: over nt then shfl over the 16 c-lanes)
    float lm[4];
#pragma unroll
    for (int rg = 0; rg < 4; rg++) {
      float mx = -1e30f;
#pragma unroll
      for (int nt = 0; nt < 16; nt++) {
        float pos = ((float)(nt*16 + c) + 0.5f) * (1.0f / 256.0f);
        float db = tv[rg] - pos;
        float sb = acc[nt][rg] * 0.125f - 10.0f * db * db;
        acc[nt][rg] = sb;
        mx = fmaxf(mx, sb);
      }
      lm[rg] = mx;
    }
#pragma unroll
    for (int s = 1; s < 16; s <<= 1)
#pragma unroll
      for (int rg = 0; rg < 4; rg++)
        lm[rg] = fmaxf(lm[rg], __shfl_xor(lm[rg], s, 64));

    // exp -> P band (wave-private), row sums
    float linv[4];
#pragma unroll
    for (int rg = 0; rg < 4; rg++) {
      float sum = 0.f;
      int row = q*4 + rg;
#pragma unroll
      for (int nt = 0; nt < 16; nt++) {
        float e = __expf(acc[nt][rg] - lm[rg]);
        sum += e;
        Pband[swz256(row, nt*16 + c)] = f2h(e);
      }
      linv[rg] = sum;
    }
#pragma unroll
    for (int s = 1; s < 16; s <<= 1)
#pragma unroll
      for (int rg = 0; rg < 4; rg++)
        linv[rg] += __shfl_xor(linv[rg], s, 64);
#pragma unroll
    for (int rg = 0; rg < 4; rg++) linv[rg] = 1.0f / linv[rg];

    // PV: M=16, N=64 dh (4 nt), K=256; A from wave-private band (compiler waitcnt)
    f32x4 oacc[4];
#pragma unroll
    for (int i = 0; i < 4; i++) oacc[i] = zero4;
    const unsigned short* vbase = vt_ws + (size_t)(w*2+h) * 64 * 256;
#pragma unroll
    for (int kt = 0; kt < 8; kt++) {
      int koff = kt * 32 + q * 8;
      half8 af = *(const half8*)&Pband[swz256(c, koff)];
#pragma unroll
      for (int nt = 0; nt < 4; nt++) {
        half8 bf = *(const half8*)(vbase + (size_t)(nt*16 + c) * 256 + koff);
        oacc[nt] = __builtin_amdgcn_mfma_f32_16x16x32_f16(af, bf, oacc[nt], 0, 0, 0);
      }
    }
    // o -> buf0 rows w*16 + row (row = b*16 + px layout for the MLP)
#pragma unroll
    for (int nt = 0; nt < 4; nt++)
#pragma unroll
      for (int rg = 0; rg < 4; rg++)
        buf0[(w*16 + q*4 + rg) * kPitch + h*64 + nt*16 + c] =
            f2h(oacc[nt][rg] * linv[rg]);
  }
  __syncthreads();   // (1) o complete in buf0; P bands dead; h0 staged

  // ================= MLP phase (R6-proven structure) =================
  f32x4 acc[16];

  // ---- P1: mod = o @ tooW + toob -> buf1 ----
#pragma unroll
  for (int i = 0; i < 16; i++) acc[i] = zero4;
  gemm4<128>(buf0, tooWt + (size_t)w * 64 * 128, acc, c, q);
  {
    float bias[4];
#pragma unroll
    for (int nt = 0; nt < 4; nt++) bias[nt] = toob[w * 64 + nt * 16 + c];
#pragma unroll
    for (int mt = 0; mt < 4; mt++)
#pragma unroll
      for (int nt = 0; nt < 4; nt++)
#pragma unroll
        for (int rg = 0; rg < 4; rg++) {
          int row = mt * 16 + q * 4 + rg, col = w * 64 + nt * 16 + c;
          buf1[row * kPitch + col] = f2h(acc[mt * 4 + nt][rg] + bias[nt]);
        }
  }
  __syncthreads();   // (2)=A: mod ready; all o reads done

  // ---- P2: m0 = relu(h0 + mod @ modW0 + b) -> buf0 ----
#pragma unroll
  for (int i = 0; i < 16; i++) acc[i] = zero4;
  gemm4<256>(buf1, modW0t + (size_t)w * 64 * 256, acc, c, q);
  {
    float bias[4], hr[4][4];
#pragma unroll
    for (int nt = 0; nt < 4; nt++) {
      int col = w * 64 + nt * 16 + c;
      bias[nt] = modb0[col];
#pragma unroll
      for (int rg = 0; rg < 4; rg++)
        hr[nt][rg] = h2f(hbuf[(q * 4 + rg) * kPitch + col]);
    }
#pragma unroll
    for (int mt = 0; mt < 4; mt++)
#pragma unroll
      for (int nt = 0; nt < 4; nt++)
#pragma unroll
        for (int rg = 0; rg < 4; rg++) {
          int row = mt * 16 + q * 4 + rg, col = w * 64 + nt * 16 + c;
          buf0[row * kPitch + col] =
              f2h(fmaxf(acc[mt * 4 + nt][rg] + bias[nt] + hr[nt][rg], 0.f));
        }
  }
  __syncthreads();   // (3)=B: h0 consumed, m0 in buf0

  // ---- P3: stage h1; m1 = relu(h1 + mod @ modW1 + b); S = m0 + m1 -> buf1 ----
#pragma unroll
  for (int i = 0; i < 2; i++) {
    int idx = i * 256 + tid;
    int p = idx >> 5, c8 = (idx & 31) * 8;
    uint4 v = *(const uint4*)(h1_hf + ((size_t)(px0 + p)) * 256 + c8);
    *(uint4*)&hbuf[p * kPitch + c8] = v;
  }
#pragma unroll
  for (int i = 0; i < 16; i++) acc[i] = zero4;
  gemm4<256>(buf1, modW1t + (size_t)w * 64 * 256, acc, c, q);
  __syncthreads();   // (4)=C: h1 staged AND all mod reads done
  {
    float bias[4], hr[4][4];
#pragma unroll
    for (int nt = 0; nt < 4; nt++) {
      int col = w * 64 + nt * 16 + c;
      bias[nt] = modb1[col];
#pragma unroll
      for (int rg = 0; rg < 4; rg++)
        hr[nt][rg] = h2f(hbuf[(q * 4 + rg) * kPitch + col]);
    }
#pragma unroll
    for (int mt = 0; mt < 4; mt++)
#pragma unroll
      for (int nt = 0; nt < 4; nt++)
#pragma unroll
        for (int rg = 0; rg < 4; rg++) {
          int row = mt * 16 + q * 4 + rg, col = w * 64 + nt * 16 + c;
          float m0v = h2f(buf0[row * kPitch + col]);
          float v = m0v + fmaxf(acc[mt * 4 + nt][rg] + bias[nt] + hr[nt][rg], 0.f);
          buf1[row * kPitch + col] = f2h(v);
        }
  }
  __syncthreads();   // (5)=D: S ready

  // ---- P4: hv1 = relu(S @ hvW0 + b); fused out epilogue ----
#pragma unroll
  for (int i = 0; i < 16; i++) acc[i] = zero4;
  gemm4<256>(buf1, hvW0t + (size_t)w * 64 * 256, acc, c, q);
  {
    float bias[4], w0v[4][3], w1v[4][3];
#pragma unroll
    for (int nt = 0; nt < 4; nt++) {
      int col = w * 64 + nt * 16 + c;
      bias[nt] = hvb0[col];
#pragma unroll
      for (int k = 0; k < 3; k++) {
        w0v[nt][k] = outW0[col * 3 + k];
        w1v[nt][k] = outW1[col * 3 + k];
      }
    }
#pragma unroll
    for (int mt = 0; mt < 4; mt++) {
      float pk[4][3];
#pragma unroll
      for (int rg = 0; rg < 4; rg++)
#pragma unroll
        for (int k = 0; k < 3; k++) pk[rg][k] = 0.f;
#pragma unroll
      for (int nt = 0; nt < 4; nt++) {
        int col = w * 64 + nt * 16 + c;
#pragma unroll
        for (int rg = 0; rg < 4; rg++) {
          int row = mt * 16 + q * 4 + rg;
          float hv1 = fmaxf(acc[mt * 4 + nt][rg] + bias[nt], 0.f);
          float m0v = h2f(buf0[row * kPitch + col]);
#pragma unroll
          for (int k = 0; k < 3; k++)
            pk[rg][k] += m0v * w0v[nt][k] + hv1 * w1v[nt][k];
        }
      }
#pragma unroll
      for (int s = 1; s < 16; s <<= 1)
#pragma unroll
        for (int rg = 0; rg < 4; rg++)
#pragma unroll
          for (int k = 0; k < 3; k++)
            pk[rg][k] += __shfl_xor(pk[rg][k], s, 64);
      if (c == 0) {
#pragma unroll
        for (int rg = 0; rg < 4; rg++) {
          int row = mt * 16 + q * 4 + rg;
#pragma unroll
          for (int k = 0; k < 3; k++)
            scratch[row * 12 + k * 4 + w] = pk[rg][k];
        }
      }
    }
  }
  __syncthreads();   // (6) scratch ready

  if (tid < 192) {
    int row = tid / 3, k = tid % 3;
    int b = row >> 4, px = px0 + (row & 15);
    float s = outb0[k] + outb1[k];
#pragma unroll
    for (int ww = 0; ww < 4; ww++) s += scratch[row * 12 + k * 4 + ww];
    dout[((size_t)b * kHW + px) * 3 + k] = s;
  }
}

// ---------------- launch ----------------
extern "C" void kernel_launch(void* const* d_in, const int* in_sizes, int n_in,
                              void* d_out, int out_size, void* d_ws, size_t ws_size,
                              hipStream_t stream) {
  const float* coords = (const float*)d_in[0];
  const float* tokens = (const float*)d_in[1];
  const float* Bq     = (const float*)d_in[2];
  const float* Bl0    = (const float*)d_in[3];
  const float* Bl1    = (const float*)d_in[4];
  const float* qW     = (const float*)d_in[5];
  const float* qb     = (const float*)d_in[6];
  const float* toqW   = (const float*)d_in[7];
  const float* tokvW  = (const float*)d_in[8];
  const float* tooW   = (const float*)d_in[9];
  const float* toob   = (const float*)d_in[10];
  const float* bwW0   = (const float*)d_in[11];
  const float* bwb0   = (const float*)d_in[12];
  const float* bwW1   = (const float*)d_in[13];
  const float* bwb1   = (const float*)d_in[14];
  const float* modW0  = (const float*)d_in[15];
  const float* modb0  = (const float*)d_in[16];
  const float* modW1  = (const float*)d_in[17];
  const float* modb1  = (const float*)d_in[18];
  const float* hvW0   = (const float*)d_in[19];
  const float* hvb0   = (const float*)d_in[20];
  const float* outW0  = (const float*)d_in[21];
  const float* outb0  = (const float*)d_in[22];
  const float* outW1  = (const float*)d_in[23];
  const float* outb1  = (const float*)d_in[24];

  char* ws = (char*)d_ws;
  unsigned short* qc_ws  = (unsigned short*)(ws + 65536);     //    4 MB
  unsigned short* h0_hf  = (unsigned short*)(ws + 4259840);   //    8 MB
  unsigned short* h1_hf  = (unsigned short*)(ws + 12648448);  //    8 MB
  unsigned short* kn_ws  = (unsigned short*)(ws + 37814272);  //  256 KB
  unsigned short* vt_ws  = (unsigned short*)(ws + 38076416);  //  256 KB
  unsigned short* tooWt  = (unsigned short*)(ws + 38338560);  //   64 KB
  unsigned short* modW0t = (unsigned short*)(ws + 38404096);  //  128 KB
  unsigned short* modW1t = (unsigned short*)(ws + 38535168);  //  128 KB
  unsigned short* hvW0t  = (unsigned short*)(ws + 38666240);  //  128 KB
  unsigned short* qWt    = (unsigned short*)(ws + 38797312);  //   32 KB
  unsigned short* bw0t   = (unsigned short*)(ws + 38830080);  //   32 KB
  unsigned short* bw1t   = (unsigned short*)(ws + 38862848);  //   32 KB
  unsigned short* toqWt  = (unsigned short*)(ws + 38895616);  //   64 KB

  wprep_kernel<<<dim3(8), 256, 0, stream>>>(
      tooW, modW0, modW1, hvW0, qW, bwW0, bwW1, toqW,
      tooWt, modW0t, modW1t, hvW0t, qWt, bw0t, bw1t, toqWt);
  feat_kernel<<<dim3(kHW / 32), 256, 0, stream>>>(
      coords, Bq, Bl0, Bl1, qb, bwb0, bwb1,
      qWt, bw0t, bw1t, toqWt,
      qc_ws, h0_hf, h1_hf);
  kv_kernel<<<dim3(kM, kB), 256, 0, stream>>>(tokens, tokvW, kn_ws, vt_ws);
  fused_kernel<<<dim3(kHW / 16), 256, 0, stream>>>(
      kn_ws, vt_ws, qc_ws, coords, h0_hf, h1_hf,
      tooWt, toob, modW0t, modb0, modW1t, modb1,
      hvW0t, hvb0, outW0, outb0, outW1, outb1, (float*)d_out);
}

// Round 10
// 274.276 us; speedup vs baseline: 1.1724x; 1.1724x over previous
//
#include <hip/hip_runtime.h>
#include <stdint.h>

constexpr int kHW = 16384;   // 128*128 pixels (grid shared across batch)
constexpr int kB  = 4;
constexpr int kM  = 256;     // tokens

typedef _Float16 half8 __attribute__((ext_vector_type(8)));  // 8 fp16 (4 VGPRs)
typedef __attribute__((ext_vector_type(4))) float f32x4;     // MFMA accum

// ---------------- helpers ----------------
__device__ __forceinline__ unsigned short f2h(float f) {
  _Float16 h = (_Float16)f;
  return __builtin_bit_cast(unsigned short, h);
}
__device__ __forceinline__ float h2f(unsigned short u) {
  return (float)__builtin_bit_cast(_Float16, u);
}
// XOR swizzle for 256-short-wide rows (8-short chunks): conflict-free b128 A-reads.
__device__ __forceinline__ int swz256(int row, int col) {
  int ch = col >> 3;
  ch = (ch & ~7) | ((ch ^ row) & 7);
  return row * 256 + ch * 8 + (col & 7);
}

// ---------------- kernel 0: weight prep (transpose + fp16) ----------------
__global__ __launch_bounds__(256) void wprep_kernel(
    const float* __restrict__ tooW, const float* __restrict__ modW0,
    const float* __restrict__ modW1, const float* __restrict__ hvW0,
    const float* __restrict__ qW, const float* __restrict__ bwW0,
    const float* __restrict__ bwW1, const float* __restrict__ toqW,
    unsigned short* __restrict__ tooWt, unsigned short* __restrict__ modW0t,
    unsigned short* __restrict__ modW1t, unsigned short* __restrict__ hvW0t,
    unsigned short* __restrict__ qWt, unsigned short* __restrict__ bw0t,
    unsigned short* __restrict__ bw1t, unsigned short* __restrict__ toqWt)
{
  int m = blockIdx.x, tid = threadIdx.x;
  const float* Ws[8] = {tooW, modW0, modW1, hvW0, qW, bwW0, bwW1, toqW};
  unsigned short* Wts[8] = {tooWt, modW0t, modW1t, hvW0t, qWt, bw0t, bw1t, toqWt};
  const int Ks[8] = {128, 256, 256, 256, 64, 64, 64, 256};
  const int Ns[8] = {256, 256, 256, 256, 256, 256, 256, 128};
  const float* W = Ws[m];
  unsigned short* Wt = Wts[m];
  int K = Ks[m], N = Ns[m];
  if (tid < N) {
    for (int kb = 0; kb < K / 8; kb++) {
      unsigned short sv[8];
#pragma unroll
      for (int i = 0; i < 8; i++)
        sv[i] = f2h(W[(kb * 8 + i) * N + tid]);   // coalesced across tid
      *(uint4*)&Wt[tid * K + kb * 8] = *(const uint4*)sv;
    }
  }
}

// ---------------- kernel 1: kv = tokens @ tokvW -> K natural + V transposed, fp16 ----------------
__global__ __launch_bounds__(256) void kv_kernel(
    const float* __restrict__ tokens, const float* __restrict__ tokvW,
    unsigned short* __restrict__ kn_ws, unsigned short* __restrict__ vt_ws)
{
  __shared__ __align__(16) float tok[256];
  int b = blockIdx.y, j = blockIdx.x, c = threadIdx.x;
  tok[c] = tokens[(b * kM + j) * 256 + c];
  __syncthreads();
  float acc = 0.f;
  for (int i4 = 0; i4 < 64; i4++) {
    float4 t4 = *(const float4*)&tok[i4 * 4];
    acc += t4.x * tokvW[(i4*4+0)*256 + c] + t4.y * tokvW[(i4*4+1)*256 + c]
         + t4.z * tokvW[(i4*4+2)*256 + c] + t4.w * tokvW[(i4*4+3)*256 + c];
  }
  unsigned short hv = f2h(acc);
  if (c < 128) {
    int h = c >> 6, dd = c & 63;
    kn_ws[((size_t)(b*2+h)*256 + j) * 64 + dd] = hv;
  } else {
    int c2 = c - 128;
    int h = c2 >> 6, dd = c2 & 63;
    vt_ws[((size_t)(b*2+h)*64 + dd) * 256 + j] = hv;
  }
}

// ---------------- kernel 2: MFMA per-pixel features (R6-proven) ----------------
constexpr int kFPitch = 72;
constexpr int kXPitch = 264;

__global__ __launch_bounds__(256, 2) void feat_kernel(
    const float* __restrict__ coords,
    const float* __restrict__ Bq, const float* __restrict__ Bl0, const float* __restrict__ Bl1,
    const float* __restrict__ qb, const float* __restrict__ bwb0, const float* __restrict__ bwb1,
    const unsigned short* __restrict__ qWt, const unsigned short* __restrict__ bw0t,
    const unsigned short* __restrict__ bw1t, const unsigned short* __restrict__ toqWt,
    unsigned short* __restrict__ qc_ws,
    unsigned short* __restrict__ h0_hf, unsigned short* __restrict__ h1_hf)
{
  __shared__ __align__(16) unsigned short ff_s[3][32][kFPitch];
  __shared__ __align__(16) unsigned short xq_s[32][kXPitch];
  __shared__ float coords_s[64];

  int tid = threadIdx.x;
  int px0 = blockIdx.x * 32;
  int w = tid >> 6, ln = tid & 63;
  int c = ln & 15, q = ln >> 4;

  if (tid < 64) coords_s[tid] = coords[px0 * 2 + tid];
  __syncthreads();

#pragma unroll
  for (int r = 0; r < 24; r++) {
    int v = r * 256 + tid;
    int mat = v >> 11;
    int p = (v >> 6) & 31;
    int f = v & 63;
    int fr = f & 31;
    const float* Bm = (mat == 0) ? Bq : (mat == 1 ? Bl0 : Bl1);
    float x = coords_s[p * 2 + 0];
    float y = coords_s[p * 2 + 1];
    float proj = 6.283185307179586f * (x * Bm[fr*2+0] + y * Bm[fr*2+1]);
    float s, cc;
    __sincosf(proj, &s, &cc);
    ff_s[mat][p][f] = f2h((f < 32) ? cc : s);
  }
  __syncthreads();

  const f32x4 zero4 = {0.f, 0.f, 0.f, 0.f};

  for (int mat = 0; mat < 3; mat++) {
    const unsigned short* Wt = (mat == 0) ? qWt : (mat == 1 ? bw0t : bw1t);
    const float* bias = (mat == 0) ? qb : (mat == 1 ? bwb0 : bwb1);
    f32x4 acc[8];
#pragma unroll
    for (int i = 0; i < 8; i++) acc[i] = zero4;
#pragma unroll
    for (int ks = 0; ks < 2; ks++) {
      int koff = ks * 32 + q * 8;
      half8 bfr[4];
#pragma unroll
      for (int nt = 0; nt < 4; nt++)
        bfr[nt] = *(const half8*)(Wt + (size_t)(w*64 + nt*16 + c) * 64 + koff);
      half8 afr[2];
#pragma unroll
      for (int mt = 0; mt < 2; mt++)
        afr[mt] = *(const half8*)(&ff_s[mat][mt*16 + c][koff]);
#pragma unroll
      for (int mt = 0; mt < 2; mt++)
#pragma unroll
        for (int nt = 0; nt < 4; nt++)
          acc[mt*4+nt] = __builtin_amdgcn_mfma_f32_16x16x32_f16(afr[mt], bfr[nt], acc[mt*4+nt], 0, 0, 0);
    }
    float bv[4];
#pragma unroll
    for (int nt = 0; nt < 4; nt++) bv[nt] = bias[w*64 + nt*16 + c];
#pragma unroll
    for (int mt = 0; mt < 2; mt++)
#pragma unroll
      for (int nt = 0; nt < 4; nt++)
#pragma unroll
        for (int rg = 0; rg < 4; rg++) {
          int row = mt*16 + q*4 + rg, col = w*64 + nt*16 + c;
          unsigned short hv = f2h(fmaxf(acc[mt*4+nt][rg] + bv[nt], 0.f));
          if (mat == 0)      xq_s[row][col] = hv;
          else if (mat == 1) h0_hf[((size_t)(px0 + row)) * 256 + col] = hv;
          else               h1_hf[((size_t)(px0 + row)) * 256 + col] = hv;
        }
  }
  __syncthreads();

  {
    f32x4 acc2[4];
#pragma unroll
    for (int i = 0; i < 4; i++) acc2[i] = zero4;
#pragma unroll
    for (int kt = 0; kt < 8; kt++) {
      int koff = kt * 32 + q * 8;
      half8 bfr[2];
#pragma unroll
      for (int nt = 0; nt < 2; nt++)
        bfr[nt] = *(const half8*)(toqWt + (size_t)(w*32 + nt*16 + c) * 256 + koff);
      half8 afr[2];
#pragma unroll
      for (int mt = 0; mt < 2; mt++)
        afr[mt] = *(const half8*)(&xq_s[mt*16 + c][koff]);
#pragma unroll
      for (int mt = 0; mt < 2; mt++)
#pragma unroll
        for (int nt = 0; nt < 2; nt++)
          acc2[mt*2+nt] = __builtin_amdgcn_mfma_f32_16x16x32_f16(afr[mt], bfr[nt], acc2[mt*2+nt], 0, 0, 0);
    }
#pragma unroll
    for (int mt = 0; mt < 2; mt++)
#pragma unroll
      for (int nt = 0; nt < 2; nt++)
#pragma unroll
        for (int rg = 0; rg < 4; rg++) {
          int row = mt*16 + q*4 + rg, col = w*32 + nt*16 + c;
          qc_ws[((size_t)(px0 + row)) * 128 + col] = f2h(acc2[mt*2+nt][rg]);
        }
  }
}

// ---------------- kernel 3: FUSED attention + MLP chain (LDS 79.1 KB -> 2 blocks/CU) ----------------
// Block = 16 px, 4 waves; wave w = batch w. Attn phase: wave-private, barrier-free.
// regB = max(buf1 64x264, 4 P bands 16x256) = 16896 shorts (R9 bug: was 21120 -> 1 block/CU).
constexpr int kPitch = 264;   // fp16 LDS pitch for mlp tiles

template <int KD>
__device__ __forceinline__ void gemm4(
    const unsigned short* abuf, const unsigned short* wt,
    f32x4* acc /*[4*4]*/, int c, int q)
{
#pragma unroll
  for (int ks = 0; ks < KD / 32; ks++) {
    int koff = ks * 32 + q * 8;
    half8 bfr[4];
#pragma unroll
    for (int nt = 0; nt < 4; nt++)
      bfr[nt] = *(const half8*)(wt + (nt * 16 + c) * KD + koff);
    half8 afr[4];
#pragma unroll
    for (int mt = 0; mt < 4; mt++)
      afr[mt] = *(const half8*)(abuf + (mt * 16 + c) * kPitch + koff);
#pragma unroll
    for (int mt = 0; mt < 4; mt++)
#pragma unroll
      for (int nt = 0; nt < 4; nt++)
        acc[mt * 4 + nt] = __builtin_amdgcn_mfma_f32_16x16x32_f16(afr[mt], bfr[nt], acc[mt * 4 + nt], 0, 0, 0);
  }
}

__global__ __launch_bounds__(256, 2) void fused_kernel(
    const unsigned short* __restrict__ kn_ws,
    const unsigned short* __restrict__ vt_ws,
    const unsigned short* __restrict__ qc_ws,
    const float* __restrict__ coords,
    const unsigned short* __restrict__ h0_hf, const unsigned short* __restrict__ h1_hf,
    const unsigned short* __restrict__ tooWt, const float* __restrict__ toob,
    const unsigned short* __restrict__ modW0t, const float* __restrict__ modb0,
    const unsigned short* __restrict__ modW1t, const float* __restrict__ modb1,
    const unsigned short* __restrict__ hvW0t, const float* __restrict__ hvb0,
    const float* __restrict__ outW0, const float* __restrict__ outb0,
    const float* __restrict__ outW1, const float* __restrict__ outb1,
    float* __restrict__ dout)
{
  __shared__ __align__(16) unsigned short buf0[64 * kPitch];  // o -> m0 (hv0)   33792 B
  __shared__ __align__(16) unsigned short regB[64 * kPitch];  // P bands | buf1  33792 B
  __shared__ __align__(16) unsigned short hbuf[16 * kPitch];  // h0, then h1      8448 B
  __shared__ __align__(16) float scratch[64 * 3 * 4];         //                  3072 B

  unsigned short* buf1  = regB;
  int tid = threadIdx.x;
  int px0 = blockIdx.x * 16;
  int w = tid >> 6, ln = tid & 63;    // wave w = batch w
  int c = ln & 15, q = ln >> 4;
  unsigned short* Pband = regB + w * 4096;   // wave-private 16x256 band

  const f32x4 zero4 = {0.f, 0.f, 0.f, 0.f};

  // ---- stage h0 early (hbuf is disjoint from P bands) ----
#pragma unroll
  for (int i = 0; i < 2; i++) {
    int idx = i * 256 + tid;              // 512 x uint4
    int p = idx >> 5, c8 = (idx & 31) * 8;
    uint4 v = *(const uint4*)(h0_hf + ((size_t)(px0 + p)) * 256 + c8);
    *(uint4*)&hbuf[p * kPitch + c8] = v;
  }

  // ---- per-lane t values for owned rows (px = px0 + q*4 + rg) ----
  float tv[4];
#pragma unroll
  for (int rg = 0; rg < 4; rg++) {
    int px = px0 + q*4 + rg;
    float x = coords[px*2 + 0], y = coords[px*2 + 1];
    int r = min(max((int)(x * 16.0f), 0), 15);
    int cl = min(max((int)(y * 16.0f), 0), 15);
    tv[rg] = (float)(r * 16 + cl) * (1.0f / 256.0f);
  }

  // ================= attention phase (barrier-free, wave = batch) =================
  for (int h = 0; h < 2; h++) {
    // QK^T: M=16 (px), N=256 (16 nt), K=64
    f32x4 acc[16];
#pragma unroll
    for (int i = 0; i < 16; i++) acc[i] = zero4;
    const unsigned short* kbase = kn_ws + (size_t)(w*2+h) * 256 * 64;
    const unsigned short* qrow = qc_ws + (size_t)(px0 + c) * 128 + h*64;
    half8 a0 = *(const half8*)(qrow + q*8);
    half8 a1 = *(const half8*)(qrow + 32 + q*8);
#pragma unroll
    for (int nt = 0; nt < 16; nt++) {
      const unsigned short* kr = kbase + (size_t)(nt*16 + c) * 64 + q*8;
      half8 b0 = *(const half8*)(kr);
      half8 b1 = *(const half8*)(kr + 32);
      acc[nt] = __builtin_amdgcn_mfma_f32_16x16x32_f16(a0, b0, acc[nt], 0, 0, 0);
      acc[nt] = __builtin_amdgcn_mfma_f32_16x16x32_f16(a1, b1, acc[nt], 0, 0, 0);
    }

    // bias + scale; row max (intra-wave: over nt then shfl over the 16 c-lanes)
    float lm[4];
#pragma unroll
    for (int rg = 0; rg < 4; rg++) {
      float mx = -1e30f;
#pragma unroll
      for (int nt = 0; nt < 16; nt++) {
        float pos = ((float)(nt*16 + c) + 0.5f) * (1.0f / 256.0f);
        float db = tv[rg] - pos;
        float sb = acc[nt][rg] * 0.125f - 10.0f * db * db;
        acc[nt][rg] = sb;
        mx = fmaxf(mx, sb);
      }
      lm[rg] = mx;
    }
#pragma unroll
    for (int s = 1; s < 16; s <<= 1)
#pragma unroll
      for (int rg = 0; rg < 4; rg++)
        lm[rg] = fmaxf(lm[rg], __shfl_xor(lm[rg], s, 64));

    // exp -> P band (wave-private), row sums
    float linv[4];
#pragma unroll
    for (int rg = 0; rg < 4; rg++) {
      float sum = 0.f;
      int row = q*4 + rg;
#pragma unroll
      for (int nt = 0; nt < 16; nt++) {
        float e = __expf(acc[nt][rg] - lm[rg]);
        sum += e;
        Pband[swz256(row, nt*16 + c)] = f2h(e);
      }
      linv[rg] = sum;
    }
#pragma unroll
    for (int s = 1; s < 16; s <<= 1)
#pragma unroll
      for (int rg = 0; rg < 4; rg++)
        linv[rg] += __shfl_xor(linv[rg], s, 64);
#pragma unroll
    for (int rg = 0; rg < 4; rg++) linv[rg] = 1.0f / linv[rg];

    // PV: M=16, N=64 dh (4 nt), K=256; A from wave-private band (compiler waitcnt)
    f32x4 oacc[4];
#pragma unroll
    for (int i = 0; i < 4; i++) oacc[i] = zero4;
    const unsigned short* vbase = vt_ws + (size_t)(w*2+h) * 64 * 256;
#pragma unroll
    for (int kt = 0; kt < 8; kt++) {
      int koff = kt * 32 + q * 8;
      half8 af = *(const half8*)&Pband[swz256(c, koff)];
#pragma unroll
      for (int nt = 0; nt < 4; nt++) {
        half8 bf = *(const half8*)(vbase + (size_t)(nt*16 + c) * 256 + koff);
        oacc[nt] = __builtin_amdgcn_mfma_f32_16x16x32_f16(af, bf, oacc[nt], 0, 0, 0);
      }
    }
    // o -> buf0 rows w*16 + row (row = b*16 + px layout for the MLP)
#pragma unroll
    for (int nt = 0; nt < 4; nt++)
#pragma unroll
      for (int rg = 0; rg < 4; rg++)
        buf0[(w*16 + q*4 + rg) * kPitch + h*64 + nt*16 + c] =
            f2h(oacc[nt][rg] * linv[rg]);
  }
  __syncthreads();   // (1) o complete in buf0; P bands dead; h0 staged

  // ================= MLP phase (R6-proven structure) =================
  f32x4 acc[16];

  // ---- P1: mod = o @ tooW + toob -> buf1 ----
#pragma unroll
  for (int i = 0; i < 16; i++) acc[i] = zero4;
  gemm4<128>(buf0, tooWt + (size_t)w * 64 * 128, acc, c, q);
  {
    float bias[4];
#pragma unroll
    for (int nt = 0; nt < 4; nt++) bias[nt] = toob[w * 64 + nt * 16 + c];
#pragma unroll
    for (int mt = 0; mt < 4; mt++)
#pragma unroll
      for (int nt = 0; nt < 4; nt++)
#pragma unroll
        for (int rg = 0; rg < 4; rg++) {
          int row = mt * 16 + q * 4 + rg, col = w * 64 + nt * 16 + c;
          buf1[row * kPitch + col] = f2h(acc[mt * 4 + nt][rg] + bias[nt]);
        }
  }
  __syncthreads();   // (2)=A: mod ready; all o reads done

  // ---- P2: m0 = relu(h0 + mod @ modW0 + b) -> buf0 ----
#pragma unroll
  for (int i = 0; i < 16; i++) acc[i] = zero4;
  gemm4<256>(buf1, modW0t + (size_t)w * 64 * 256, acc, c, q);
  {
    float bias[4], hr[4][4];
#pragma unroll
    for (int nt = 0; nt < 4; nt++) {
      int col = w * 64 + nt * 16 + c;
      bias[nt] = modb0[col];
#pragma unroll
      for (int rg = 0; rg < 4; rg++)
        hr[nt][rg] = h2f(hbuf[(q * 4 + rg) * kPitch + col]);
    }
#pragma unroll
    for (int mt = 0; mt < 4; mt++)
#pragma unroll
      for (int nt = 0; nt < 4; nt++)
#pragma unroll
        for (int rg = 0; rg < 4; rg++) {
          int row = mt * 16 + q * 4 + rg, col = w * 64 + nt * 16 + c;
          buf0[row * kPitch + col] =
              f2h(fmaxf(acc[mt * 4 + nt][rg] + bias[nt] + hr[nt][rg], 0.f));
        }
  }
  __syncthreads();   // (3)=B: h0 consumed, m0 in buf0

  // ---- P3: stage h1; m1 = relu(h1 + mod @ modW1 + b); S = m0 + m1 -> buf1 ----
#pragma unroll
  for (int i = 0; i < 2; i++) {
    int idx = i * 256 + tid;
    int p = idx >> 5, c8 = (idx & 31) * 8;
    uint4 v = *(const uint4*)(h1_hf + ((size_t)(px0 + p)) * 256 + c8);
    *(uint4*)&hbuf[p * kPitch + c8] = v;
  }
#pragma unroll
  for (int i = 0; i < 16; i++) acc[i] = zero4;
  gemm4<256>(buf1, modW1t + (size_t)w * 64 * 256, acc, c, q);
  __syncthreads();   // (4)=C: h1 staged AND all mod reads done
  {
    float bias[4], hr[4][4];
#pragma unroll
    for (int nt = 0; nt < 4; nt++) {
      int col = w * 64 + nt * 16 + c;
      bias[nt] = modb1[col];
#pragma unroll
      for (int rg = 0; rg < 4; rg++)
        hr[nt][rg] = h2f(hbuf[(q * 4 + rg) * kPitch + col]);
    }
#pragma unroll
    for (int mt = 0; mt < 4; mt++)
#pragma unroll
      for (int nt = 0; nt < 4; nt++)
#pragma unroll
        for (int rg = 0; rg < 4; rg++) {
          int row = mt * 16 + q * 4 + rg, col = w * 64 + nt * 16 + c;
          float m0v = h2f(buf0[row * kPitch + col]);
          float v = m0v + fmaxf(acc[mt * 4 + nt][rg] + bias[nt] + hr[nt][rg], 0.f);
          buf1[row * kPitch + col] = f2h(v);
        }
  }
  __syncthreads();   // (5)=D: S ready

  // ---- P4: hv1 = relu(S @ hvW0 + b); fused out epilogue ----
#pragma unroll
  for (int i = 0; i < 16; i++) acc[i] = zero4;
  gemm4<256>(buf1, hvW0t + (size_t)w * 64 * 256, acc, c, q);
  {
    float bias[4], w0v[4][3], w1v[4][3];
#pragma unroll
    for (int nt = 0; nt < 4; nt++) {
      int col = w * 64 + nt * 16 + c;
      bias[nt] = hvb0[col];
#pragma unroll
      for (int k = 0; k < 3; k++) {
        w0v[nt][k] = outW0[col * 3 + k];
        w1v[nt][k] = outW1[col * 3 + k];
      }
    }
#pragma unroll
    for (int mt = 0; mt < 4; mt++) {
      float pk[4][3];
#pragma unroll
      for (int rg = 0; rg < 4; rg++)
#pragma unroll
        for (int k = 0; k < 3; k++) pk[rg][k] = 0.f;
#pragma unroll
      for (int nt = 0; nt < 4; nt++) {
        int col = w * 64 + nt * 16 + c;
#pragma unroll
        for (int rg = 0; rg < 4; rg++) {
          int row = mt * 16 + q * 4 + rg;
          float hv1 = fmaxf(acc[mt * 4 + nt][rg] + bias[nt], 0.f);
          float m0v = h2f(buf0[row * kPitch + col]);
#pragma unroll
          for (int k = 0; k < 3; k++)
            pk[rg][k] += m0v * w0v[nt][k] + hv1 * w1v[nt][k];
        }
      }
#pragma unroll
      for (int s = 1; s < 16; s <<= 1)
#pragma unroll
        for (int rg = 0; rg < 4; rg++)
#pragma unroll
          for (int k = 0; k < 3; k++)
            pk[rg][k] += __shfl_xor(pk[rg][k], s, 64);
      if (c == 0) {
#pragma unroll
        for (int rg = 0; rg < 4; rg++) {
          int row = mt * 16 + q * 4 + rg;
#pragma unroll
          for (int k = 0; k < 3; k++)
            scratch[row * 12 + k * 4 + w] = pk[rg][k];
        }
      }
    }
  }
  __syncthreads();   // (6) scratch ready

  if (tid < 192) {
    int row = tid / 3, k = tid % 3;
    int b = row >> 4, px = px0 + (row & 15);
    float s = outb0[k] + outb1[k];
#pragma unroll
    for (int ww = 0; ww < 4; ww++) s += scratch[row * 12 + k * 4 + ww];
    dout[((size_t)b * kHW + px) * 3 + k] = s;
  }
}

// ---------------- launch ----------------
extern "C" void kernel_launch(void* const* d_in, const int* in_sizes, int n_in,
                              void* d_out, int out_size, void* d_ws, size_t ws_size,
                              hipStream_t stream) {
  const float* coords = (const float*)d_in[0];
  const float* tokens = (const float*)d_in[1];
  const float* Bq     = (const float*)d_in[2];
  const float* Bl0    = (const float*)d_in[3];
  const float* Bl1    = (const float*)d_in[4];
  const float* qW     = (const float*)d_in[5];
  const float* qb     = (const float*)d_in[6];
  const float* toqW   = (const float*)d_in[7];
  const float* tokvW  = (const float*)d_in[8];
  const float* tooW   = (const float*)d_in[9];
  const float* toob   = (const float*)d_in[10];
  const float* bwW0   = (const float*)d_in[11];
  const float* bwb0   = (const float*)d_in[12];
  const float* bwW1   = (const float*)d_in[13];
  const float* bwb1   = (const float*)d_in[14];
  const float* modW0  = (const float*)d_in[15];
  const float* modb0  = (const float*)d_in[16];
  const float* modW1  = (const float*)d_in[17];
  const float* modb1  = (const float*)d_in[18];
  const float* hvW0   = (const float*)d_in[19];
  const float* hvb0   = (const float*)d_in[20];
  const float* outW0  = (const float*)d_in[21];
  const float* outb0  = (const float*)d_in[22];
  const float* outW1  = (const float*)d_in[23];
  const float* outb1  = (const float*)d_in[24];

  char* ws = (char*)d_ws;
  unsigned short* qc_ws  = (unsigned short*)(ws + 65536);     //    4 MB
  unsigned short* h0_hf  = (unsigned short*)(ws + 4259840);   //    8 MB
  unsigned short* h1_hf  = (unsigned short*)(ws + 12648448);  //    8 MB
  unsigned short* kn_ws  = (unsigned short*)(ws + 37814272);  //  256 KB
  unsigned short* vt_ws  = (unsigned short*)(ws + 38076416);  //  256 KB
  unsigned short* tooWt  = (unsigned short*)(ws + 38338560);  //   64 KB
  unsigned short* modW0t = (unsigned short*)(ws + 38404096);  //  128 KB
  unsigned short* modW1t = (unsigned short*)(ws + 38535168);  //  128 KB
  unsigned short* hvW0t  = (unsigned short*)(ws + 38666240);  //  128 KB
  unsigned short* qWt    = (unsigned short*)(ws + 38797312);  //   32 KB
  unsigned short* bw0t   = (unsigned short*)(ws + 38830080);  //   32 KB
  unsigned short* bw1t   = (unsigned short*)(ws + 38862848);  //   32 KB
  unsigned short* toqWt  = (unsigned short*)(ws + 38895616);  //   64 KB

  wprep_kernel<<<dim3(8), 256, 0, stream>>>(
      tooW, modW0, modW1, hvW0, qW, bwW0, bwW1, toqW,
      tooWt, modW0t, modW1t, hvW0t, qWt, bw0t, bw1t, toqWt);
  feat_kernel<<<dim3(kHW / 32), 256, 0, stream>>>(
      coords, Bq, Bl0, Bl1, qb, bwb0, bwb1,
      qWt, bw0t, bw1t, toqWt,
      qc_ws, h0_hf, h1_hf);
  kv_kernel<<<dim3(kM, kB), 256, 0, stream>>>(tokens, tokvW, kn_ws, vt_ws);
  fused_kernel<<<dim3(kHW / 16), 256, 0, stream>>>(
      kn_ws, vt_ws, qc_ws, coords, h0_hf, h1_hf,
      tooWt, toob, modW0t, modb0, modW1t, modb1,
      hvW0t, hvb0, outW0, outb0, outW1, outb1, (float*)d_out);
}